// Round 4
// baseline (147.621 us; speedup 1.0000x reference)
//
#include <hip/hip_runtime.h>

typedef short short8 __attribute__((ext_vector_type(8)));
typedef float floatx4 __attribute__((ext_vector_type(4)));

// Native bf16 conversion: compiler emits packed v_cvt_pk_bf16_f32 (RTNE).
__device__ __forceinline__ short f2bf(float f) {
    __bf16 h = (__bf16)f;
    return __builtin_bit_cast(short, h);
}

// Convert lora_A (4096x64) and lora_B (64x4096) fp32 -> bf16 in MFMA B-operand
// fragment layout for mfma_f32_16x16x32_bf16:
//   B-operand: lane l holds B[k][col] with col = l&15, k = 8*(l>>4) + j, j=0..7
__global__ __launch_bounds__(256) void conv_ab(
    const float* __restrict__ A, const float* __restrict__ B,
    short* __restrict__ Abf, short* __restrict__ Bbf) {
    int i = blockIdx.x * 256 + threadIdx.x;   // 0 .. 262143
    int j    = i & 7;
    int lane = (i >> 3) & 63;
    int hi   = i >> 9;                        // A: ks*4+nt ; B: ct*2+ks
    int krow = 8 * (lane >> 4) + j;
    int cc   = lane & 15;
    {   // A fragments
        int ks = hi >> 2, nt = hi & 3;
        int k = ks * 32 + krow;
        int c = nt * 16 + cc;
        Abf[i] = f2bf(A[(size_t)k * 64 + c]);
    }
    {   // B fragments
        int ct = hi >> 1, ks = hi & 1;
        int k = ks * 32 + krow;
        int c = ct * 16 + cc;
        Bbf[i] = f2bf(B[(size_t)k * 4096 + c]);
    }
}

// Fused, 512 threads = 8 waves per block of 16 rows.
//   phase 1: t[16][64] = x[rows]@A  (split-K 512/wave, LDS f32 reduce -> bf16 LDS)
//   phase 2: out[rows][cols] = (t@B) * tw * 2  (wave w owns 512 cols)
__global__ __launch_bounds__(512, 4) void fused(
    const float* __restrict__ x, const float* __restrict__ tw,
    const short* __restrict__ Abf, const short* __restrict__ Bbf,
    float* __restrict__ out) {
    __shared__ float red[8][16][65];      // per-wave f32 partials (33.3 KB)
    __shared__ short tl[16][80];          // reduced t, bf16 (2.6 KB)

    const int lane = threadIdx.x & 63;
    const int wave = threadIdx.x >> 6;    // 0..7
    const int rowbase = blockIdx.x * 16;
    const int rrow = lane & 15;
    const int kgrp = lane >> 4;           // 0..3
    const int kofs = kgrp * 8;

    // ---------------- phase 1: t = x @ A, split-K 512 per wave ----------------
    {
        const int row = rowbase + rrow;
        const bool active = (tw[row] != 0.0f);
        const float* xp = x + (size_t)row * 4096 + wave * 512 + kofs;
        // Abf8[(ksg*4 + nt)*64 + lane], ksg = wave*16 + ks
        const short8* ap = (const short8*)Abf + (size_t)wave * 4096 + lane;

        floatx4 acc[4] = {{0,0,0,0},{0,0,0,0},{0,0,0,0},{0,0,0,0}};
        #pragma unroll 4
        for (int ks = 0; ks < 16; ++ks) {
            short8 xa = (short8)0;
            if (active) {
                floatx4 x0 = *(const floatx4*)(xp + ks * 32);
                floatx4 x1 = *(const floatx4*)(xp + ks * 32 + 4);
                xa[0] = f2bf(x0[0]); xa[1] = f2bf(x0[1]);
                xa[2] = f2bf(x0[2]); xa[3] = f2bf(x0[3]);
                xa[4] = f2bf(x1[0]); xa[5] = f2bf(x1[1]);
                xa[6] = f2bf(x1[2]); xa[7] = f2bf(x1[3]);
            }
            short8 b0 = ap[ks * 256 + 0 * 64];
            short8 b1 = ap[ks * 256 + 1 * 64];
            short8 b2 = ap[ks * 256 + 2 * 64];
            short8 b3 = ap[ks * 256 + 3 * 64];
            acc[0] = __builtin_amdgcn_mfma_f32_16x16x32_bf16(xa, b0, acc[0], 0, 0, 0);
            acc[1] = __builtin_amdgcn_mfma_f32_16x16x32_bf16(xa, b1, acc[1], 0, 0, 0);
            acc[2] = __builtin_amdgcn_mfma_f32_16x16x32_bf16(xa, b2, acc[2], 0, 0, 0);
            acc[3] = __builtin_amdgcn_mfma_f32_16x16x32_bf16(xa, b3, acc[3], 0, 0, 0);
        }
        // D layout: col = lane&15 (in n-tile), row = 4*kgrp + b
        #pragma unroll
        for (int nt = 0; nt < 4; ++nt)
            #pragma unroll
            for (int b = 0; b < 4; ++b)
                red[wave][kgrp * 4 + b][nt * 16 + rrow] = acc[nt][b];
    }
    __syncthreads();
    #pragma unroll
    for (int e = threadIdx.x; e < 1024; e += 512) {
        int r = e >> 6, c = e & 63;
        float s = red[0][r][c] + red[1][r][c] + red[2][r][c] + red[3][r][c]
                + red[4][r][c] + red[5][r][c] + red[6][r][c] + red[7][r][c];
        tl[r][c] = f2bf(s);
    }
    __syncthreads();

    // ---------------- phase 2: out = (t @ B) * tw * 2 ----------------
    // A-operand: lane holds t[rrow][k], k = kofs+j (a0), 32+kofs+j (a1)
    short8 a0 = *(const short8*)&tl[rrow][kofs];
    short8 a1 = *(const short8*)&tl[rrow][32 + kofs];

    float w[4];
    #pragma unroll
    for (int b = 0; b < 4; ++b) w[b] = tw[rowbase + kgrp * 4 + b] * 2.0f;

    const short8* bp0 = (const short8*)Bbf;
    const int r0 = rowbase + kgrp * 4;

    #pragma unroll 2
    for (int tt = 0; tt < 8; ++tt) {
        const int colbase = wave * 512 + tt * 64;
        const int ctb = colbase >> 4;
        floatx4 acc[4] = {{0,0,0,0},{0,0,0,0},{0,0,0,0},{0,0,0,0}};
        #pragma unroll
        for (int nt = 0; nt < 4; ++nt) {
            short8 b0 = bp0[((ctb + nt) * 2 + 0) * 64 + lane];
            short8 b1 = bp0[((ctb + nt) * 2 + 1) * 64 + lane];
            acc[nt] = __builtin_amdgcn_mfma_f32_16x16x32_bf16(a0, b0, acc[nt], 0, 0, 0);
            acc[nt] = __builtin_amdgcn_mfma_f32_16x16x32_bf16(a1, b1, acc[nt], 0, 0, 0);
        }
        #pragma unroll
        for (int nt = 0; nt < 4; ++nt) {
            size_t co = (size_t)colbase + nt * 16 + rrow;
            #pragma unroll
            for (int b = 0; b < 4; ++b)
                out[(size_t)(r0 + b) * 4096 + co] = acc[nt][b] * w[b];
        }
    }
}

extern "C" void kernel_launch(void* const* d_in, const int* in_sizes, int n_in,
                              void* d_out, int out_size, void* d_ws, size_t ws_size,
                              hipStream_t stream) {
    const float* x  = (const float*)d_in[0];   // (8,2048,4096)
    const float* tw = (const float*)d_in[1];   // (8,2048)
    const float* A  = (const float*)d_in[2];   // (4096,64)
    const float* B  = (const float*)d_in[3];   // (64,4096)
    float* out = (float*)d_out;                // (8,2048,4096) fp32

    short* Abf = (short*)d_ws;                 // 262144 bf16 = 512 KB
    short* Bbf = Abf + 262144;                 // 512 KB

    conv_ab<<<1024, 256, 0, stream>>>(A, B, Abf, Bbf);
    fused<<<1024, 512, 0, stream>>>(x, tw, Abf, Bbf, out);
}

// Round 5
// 120.228 us; speedup vs baseline: 1.2278x; 1.2278x over previous
//
#include <hip/hip_runtime.h>

typedef short short8 __attribute__((ext_vector_type(8)));
typedef float floatx4 __attribute__((ext_vector_type(4)));

// Native bf16 conversion: compiler emits packed v_cvt_pk_bf16_f32 (RTNE).
__device__ __forceinline__ short f2bf(float f) {
    __bf16 h = (__bf16)f;
    return __builtin_bit_cast(short, h);
}

// Convert lora_A (4096x64) and lora_B (64x4096) fp32 -> bf16 in MFMA fragment
// layout for mfma_f32_16x16x32_bf16:
//   lane l holds elem[k][c] with c = l&15, k = 8*(l>>4) + j, j=0..7
// (A- and B-operand 16x16 layouts are lane-mirrors, so one packing serves both.)
__global__ __launch_bounds__(256) void conv_ab(
    const float* __restrict__ A, const float* __restrict__ B,
    short* __restrict__ Abf, short* __restrict__ Bbf) {
    int i = blockIdx.x * 256 + threadIdx.x;   // 0 .. 262143
    int j    = i & 7;
    int lane = (i >> 3) & 63;
    int hi   = i >> 9;                        // A: ks*4+nt ; B: ct*2+ks
    int krow = 8 * (lane >> 4) + j;
    int cc   = lane & 15;
    {   // A fragments
        int ks = hi >> 2, nt = hi & 3;
        int k = ks * 32 + krow;
        int c = nt * 16 + cc;
        Abf[i] = f2bf(A[(size_t)k * 64 + c]);
    }
    {   // B fragments
        int ct = hi >> 1, ks = hi & 1;
        int k = ks * 32 + krow;
        int c = ct * 16 + cc;
        Bbf[i] = f2bf(B[(size_t)k * 4096 + c]);
    }
}

// Fused, 256 threads = 4 waves per block of 16 rows (R3 geometry).
//   phase 1: t[16][64] = x[rows]@A  (split-K 1024/wave, LDS f32 reduce -> bf16 LDS)
//   phase 2: out = (t@B)*tw*2, operand-SWAPPED mfma so each lane holds one
//            out-row x 4 consecutive cols -> single float4 nontemporal store.
__global__ __launch_bounds__(256) void fused(
    const float* __restrict__ x, const float* __restrict__ tw,
    const short* __restrict__ Abf, const short* __restrict__ Bbf,
    float* __restrict__ out) {
    __shared__ float red[4][16][65];      // per-wave f32 partials (16.6 KB)
    __shared__ short tl[16][80];          // reduced t, bf16 (2.5 KB)

    const int lane = threadIdx.x & 63;
    const int wave = threadIdx.x >> 6;    // 0..3
    const int rowbase = blockIdx.x * 16;
    const int rrow = lane & 15;
    const int kgrp = lane >> 4;           // 0..3
    const int kofs = kgrp * 8;

    // ---------------- phase 1: t = x @ A, split-K 1024 per wave ----------------
    {
        const int row = rowbase + rrow;
        const bool active = (tw[row] != 0.0f);
        const float* xp = x + (size_t)row * 4096 + wave * 1024 + kofs;
        // Abf8[(ksg*4 + nt)*64 + lane], ksg = wave*32 + ks
        const short8* ap = (const short8*)Abf + (size_t)wave * 8192 + lane;

        floatx4 acc[4] = {{0,0,0,0},{0,0,0,0},{0,0,0,0},{0,0,0,0}};
        #pragma unroll 4
        for (int ks = 0; ks < 32; ++ks) {
            short8 xa = (short8)0;
            if (active) {
                floatx4 x0 = *(const floatx4*)(xp + ks * 32);
                floatx4 x1 = *(const floatx4*)(xp + ks * 32 + 4);
                xa[0] = f2bf(x0[0]); xa[1] = f2bf(x0[1]);
                xa[2] = f2bf(x0[2]); xa[3] = f2bf(x0[3]);
                xa[4] = f2bf(x1[0]); xa[5] = f2bf(x1[1]);
                xa[6] = f2bf(x1[2]); xa[7] = f2bf(x1[3]);
            }
            short8 b0 = ap[ks * 256 + 0 * 64];
            short8 b1 = ap[ks * 256 + 1 * 64];
            short8 b2 = ap[ks * 256 + 2 * 64];
            short8 b3 = ap[ks * 256 + 3 * 64];
            acc[0] = __builtin_amdgcn_mfma_f32_16x16x32_bf16(xa, b0, acc[0], 0, 0, 0);
            acc[1] = __builtin_amdgcn_mfma_f32_16x16x32_bf16(xa, b1, acc[1], 0, 0, 0);
            acc[2] = __builtin_amdgcn_mfma_f32_16x16x32_bf16(xa, b2, acc[2], 0, 0, 0);
            acc[3] = __builtin_amdgcn_mfma_f32_16x16x32_bf16(xa, b3, acc[3], 0, 0, 0);
        }
        // D layout: col = lane&15 (t-col in n-tile), row = 4*kgrp + b (t-row)
        #pragma unroll
        for (int nt = 0; nt < 4; ++nt)
            #pragma unroll
            for (int b = 0; b < 4; ++b)
                red[wave][kgrp * 4 + b][nt * 16 + rrow] = acc[nt][b];
    }
    __syncthreads();
    #pragma unroll
    for (int e = threadIdx.x; e < 1024; e += 256) {
        int r = e >> 6, c = e & 63;
        tl[r][c] = f2bf(red[0][r][c] + red[1][r][c] + red[2][r][c] + red[3][r][c]);
    }
    __syncthreads();

    // ---------------- phase 2: out = (t @ B) * tw * 2, operand-swapped ----------------
    // t fragment (serves as MFMA *B*-operand): lane holds t[rrow][k], k = kofs+j
    short8 a0 = *(const short8*)&tl[rrow][kofs];
    short8 a1 = *(const short8*)&tl[rrow][32 + kofs];

    const float w = tw[rowbase + rrow] * 2.0f;   // one out-row per lane
    const short8* bp0 = (const short8*)Bbf;
    const size_t orow = (size_t)(rowbase + rrow) * 4096;

    #pragma unroll 2
    for (int tt = 0; tt < 16; ++tt) {
        const int colbase = wave * 1024 + tt * 64;
        const int ctb = colbase >> 4;
        floatx4 acc[4] = {{0,0,0,0},{0,0,0,0},{0,0,0,0},{0,0,0,0}};
        #pragma unroll
        for (int nt = 0; nt < 4; ++nt) {
            short8 b0 = bp0[((ctb + nt) * 2 + 0) * 64 + lane];
            short8 b1 = bp0[((ctb + nt) * 2 + 1) * 64 + lane];
            // swapped: Bmat fragment as A-operand, t fragment as B-operand
            // -> lane holds out[row = rrow][cols = colbase + nt*16 + kgrp*4 + 0..3]
            acc[nt] = __builtin_amdgcn_mfma_f32_16x16x32_bf16(b0, a0, acc[nt], 0, 0, 0);
            acc[nt] = __builtin_amdgcn_mfma_f32_16x16x32_bf16(b1, a1, acc[nt], 0, 0, 0);
        }
        #pragma unroll
        for (int nt = 0; nt < 4; ++nt) {
            floatx4 v = acc[nt];
            v[0] *= w; v[1] *= w; v[2] *= w; v[3] *= w;
            float* p = out + orow + colbase + nt * 16 + kgrp * 4;
            __builtin_nontemporal_store(v, (floatx4*)p);
        }
    }
}

extern "C" void kernel_launch(void* const* d_in, const int* in_sizes, int n_in,
                              void* d_out, int out_size, void* d_ws, size_t ws_size,
                              hipStream_t stream) {
    const float* x  = (const float*)d_in[0];   // (8,2048,4096)
    const float* tw = (const float*)d_in[1];   // (8,2048)
    const float* A  = (const float*)d_in[2];   // (4096,64)
    const float* B  = (const float*)d_in[3];   // (64,4096)
    float* out = (float*)d_out;                // (8,2048,4096) fp32

    short* Abf = (short*)d_ws;                 // 262144 bf16 = 512 KB
    short* Bbf = Abf + 262144;                 // 512 KB

    conv_ab<<<1024, 256, 0, stream>>>(A, B, Abf, Bbf);
    fused<<<1024, 256, 0, stream>>>(x, tw, Abf, Bbf, out);
}

// Round 6
// 105.811 us; speedup vs baseline: 1.3951x; 1.1363x over previous
//
#include <hip/hip_runtime.h>

typedef short short8 __attribute__((ext_vector_type(8)));
typedef float floatx4 __attribute__((ext_vector_type(4)));

// Native bf16 conversion: compiler emits packed v_cvt_pk_bf16_f32 (RTNE).
__device__ __forceinline__ short f2bf(float f) {
    __bf16 h = (__bf16)f;
    return __builtin_bit_cast(short, h);
}

// Convert lora_A (4096x64) and lora_B (64x4096) fp32 -> bf16 in MFMA fragment
// layout for mfma_f32_16x16x32_bf16:
//   lane l holds elem[k][c] with c = l&15, k = 8*(l>>4) + j, j=0..7
__global__ __launch_bounds__(256) void conv_ab(
    const float* __restrict__ A, const float* __restrict__ B,
    short* __restrict__ Abf, short* __restrict__ Bbf) {
    int i = blockIdx.x * 256 + threadIdx.x;   // 0 .. 262143
    int j    = i & 7;
    int lane = (i >> 3) & 63;
    int hi   = i >> 9;                        // A: ks*4+nt ; B: ct*2+ks
    int krow = 8 * (lane >> 4) + j;
    int cc   = lane & 15;
    {   // A fragments
        int ks = hi >> 2, nt = hi & 3;
        int k = ks * 32 + krow;
        int c = nt * 16 + cc;
        Abf[i] = f2bf(A[(size_t)k * 64 + c]);
    }
    {   // B fragments
        int ct = hi >> 1, ks = hi & 1;
        int k = ks * 32 + krow;
        int c = ct * 16 + cc;
        Bbf[i] = f2bf(B[(size_t)k * 4096 + c]);
    }
}

// Fused, 256 threads = 4 waves per block of 16 rows.
//   phase 1: t[16][64] = x[rows]@A, split-K 1024/wave, explicit 1-ahead
//            prefetch (x pair + 4 A-frags) enabled by 128-VGPR budget.
//   phase 2: out = (t@B)*tw*2, operand-swapped mfma -> float4 NT stores.
__global__ __launch_bounds__(256, 4) void fused(
    const float* __restrict__ x, const float* __restrict__ tw,
    const short* __restrict__ Abf, const short* __restrict__ Bbf,
    float* __restrict__ out) {
    __shared__ float red[4][16][65];      // per-wave f32 partials (16.6 KB)
    __shared__ short tl[16][80];          // reduced t, bf16 (2.5 KB)

    const int lane = threadIdx.x & 63;
    const int wave = threadIdx.x >> 6;    // 0..3
    const int rowbase = blockIdx.x * 16;
    const int rrow = lane & 15;
    const int kgrp = lane >> 4;           // 0..3
    const int kofs = kgrp * 8;

    // ---------------- phase 1: t = x @ A, split-K 1024 per wave ----------------
    {
        const int row = rowbase + rrow;
        const bool active = (tw[row] != 0.0f);
        const floatx4* xv = (const floatx4*)(x + (size_t)row * 4096 + wave * 1024 + kofs);
        // Abf8[(ksg*4 + nt)*64 + lane], ksg = wave*32 + ks
        const short8* ap = (const short8*)Abf + (size_t)wave * 8192 + lane;

        floatx4 acc0 = {0,0,0,0}, acc1 = {0,0,0,0}, acc2 = {0,0,0,0}, acc3 = {0,0,0,0};

        // prologue: loads for ks = 0
        floatx4 cx0 = {0,0,0,0}, cx1 = {0,0,0,0};
        if (active) { cx0 = xv[0]; cx1 = xv[1]; }
        short8 cb0 = ap[0], cb1 = ap[64], cb2 = ap[128], cb3 = ap[192];

        #pragma unroll 4
        for (int ks = 0; ks < 32; ++ks) {
            // prefetch ks+1 (clamped; last iter re-loads ks=31, harmless)
            const int kn = (ks + 1 < 32) ? ks + 1 : 31;
            floatx4 nx0 = {0,0,0,0}, nx1 = {0,0,0,0};
            if (active) { nx0 = xv[kn * 8]; nx1 = xv[kn * 8 + 1]; }
            short8 nb0 = ap[kn * 256 + 0 * 64];
            short8 nb1 = ap[kn * 256 + 1 * 64];
            short8 nb2 = ap[kn * 256 + 2 * 64];
            short8 nb3 = ap[kn * 256 + 3 * 64];

            short8 xa;
            xa[0] = f2bf(cx0[0]); xa[1] = f2bf(cx0[1]);
            xa[2] = f2bf(cx0[2]); xa[3] = f2bf(cx0[3]);
            xa[4] = f2bf(cx1[0]); xa[5] = f2bf(cx1[1]);
            xa[6] = f2bf(cx1[2]); xa[7] = f2bf(cx1[3]);

            acc0 = __builtin_amdgcn_mfma_f32_16x16x32_bf16(xa, cb0, acc0, 0, 0, 0);
            acc1 = __builtin_amdgcn_mfma_f32_16x16x32_bf16(xa, cb1, acc1, 0, 0, 0);
            acc2 = __builtin_amdgcn_mfma_f32_16x16x32_bf16(xa, cb2, acc2, 0, 0, 0);
            acc3 = __builtin_amdgcn_mfma_f32_16x16x32_bf16(xa, cb3, acc3, 0, 0, 0);

            cx0 = nx0; cx1 = nx1;
            cb0 = nb0; cb1 = nb1; cb2 = nb2; cb3 = nb3;
        }

        // D layout: col = lane&15 (t-col in n-tile), row = 4*kgrp + b (t-row)
        floatx4 accs[4] = {acc0, acc1, acc2, acc3};
        #pragma unroll
        for (int nt = 0; nt < 4; ++nt)
            #pragma unroll
            for (int b = 0; b < 4; ++b)
                red[wave][kgrp * 4 + b][nt * 16 + rrow] = accs[nt][b];
    }
    __syncthreads();
    #pragma unroll
    for (int e = threadIdx.x; e < 1024; e += 256) {
        int r = e >> 6, c = e & 63;
        tl[r][c] = f2bf(red[0][r][c] + red[1][r][c] + red[2][r][c] + red[3][r][c]);
    }
    __syncthreads();

    // ---------------- phase 2: out = (t @ B) * tw * 2, operand-swapped ----------------
    // t fragment (serves as MFMA *B*-operand): lane holds t[rrow][k], k = kofs+j
    short8 a0 = *(const short8*)&tl[rrow][kofs];
    short8 a1 = *(const short8*)&tl[rrow][32 + kofs];

    const float w = tw[rowbase + rrow] * 2.0f;   // one out-row per lane
    const short8* bp0 = (const short8*)Bbf;
    const size_t orow = (size_t)(rowbase + rrow) * 4096;

    #pragma unroll 2
    for (int tt = 0; tt < 16; ++tt) {
        const int colbase = wave * 1024 + tt * 64;
        const int ctb = colbase >> 4;
        floatx4 acc[4] = {{0,0,0,0},{0,0,0,0},{0,0,0,0},{0,0,0,0}};
        #pragma unroll
        for (int nt = 0; nt < 4; ++nt) {
            short8 b0 = bp0[((ctb + nt) * 2 + 0) * 64 + lane];
            short8 b1 = bp0[((ctb + nt) * 2 + 1) * 64 + lane];
            // swapped: Bmat fragment as A-operand, t fragment as B-operand
            // -> lane holds out[row = rrow][cols = colbase + nt*16 + kgrp*4 + 0..3]
            acc[nt] = __builtin_amdgcn_mfma_f32_16x16x32_bf16(b0, a0, acc[nt], 0, 0, 0);
            acc[nt] = __builtin_amdgcn_mfma_f32_16x16x32_bf16(b1, a1, acc[nt], 0, 0, 0);
        }
        #pragma unroll
        for (int nt = 0; nt < 4; ++nt) {
            floatx4 v = acc[nt];
            v[0] *= w; v[1] *= w; v[2] *= w; v[3] *= w;
            float* p = out + orow + colbase + nt * 16 + kgrp * 4;
            __builtin_nontemporal_store(v, (floatx4*)p);
        }
    }
}

extern "C" void kernel_launch(void* const* d_in, const int* in_sizes, int n_in,
                              void* d_out, int out_size, void* d_ws, size_t ws_size,
                              hipStream_t stream) {
    const float* x  = (const float*)d_in[0];   // (8,2048,4096)
    const float* tw = (const float*)d_in[1];   // (8,2048)
    const float* A  = (const float*)d_in[2];   // (4096,64)
    const float* B  = (const float*)d_in[3];   // (64,4096)
    float* out = (float*)d_out;                // (8,2048,4096) fp32

    short* Abf = (short*)d_ws;                 // 262144 bf16 = 512 KB
    short* Bbf = Abf + 262144;                 // 512 KB

    conv_ab<<<1024, 256, 0, stream>>>(A, B, Abf, Bbf);
    fused<<<1024, 256, 0, stream>>>(x, tw, Abf, Bbf, out);
}